// Round 1
// baseline (1067.434 us; speedup 1.0000x reference)
//
#include <hip/hip_runtime.h>

#define N_PTS 262144
#define X_STRIDE 79

using floatx4  = __attribute__((ext_vector_type(4))) float;
using half8    = __attribute__((ext_vector_type(8))) _Float16;
using ushort4v = __attribute__((ext_vector_type(4))) unsigned short;

__device__ __forceinline__ unsigned short f2h(float f) {
  _Float16 h = (_Float16)f;
  return __builtin_bit_cast(unsigned short, h);
}

// ---- weight table (transposed fp16, W^T[n][k], zero padded) ----------------
// layer:        fw1 fw2 uw1 uw2 bw1 bw2 bw3 nw0 nw2 nw4 nw6 nw8
__device__ const int T_KS[12]  = {63, 64, 63,128,128, 64, 64,140,256,396,256,256};
__device__ const int T_NS[12]  = {64, 64,128, 64, 64, 64, 64,256,256,256,256, 12};
__device__ const int T_KP[12]  = {64, 64, 64,128,128, 64, 64,160,256,416,256,256};
__device__ const int T_NP[12]  = {64, 64,128, 64, 64, 64, 64,256,256,256,256, 16};
__device__ const int T_OFF[13] = {0,4096,8192,16384,24576,32768,36864,40960,
                                  81920,147456,253952,319488,323584};
#define OFF_FW1 0
#define OFF_FW2 4096
#define OFF_UW1 8192
#define OFF_UW2 16384
#define OFF_BW1 24576
#define OFF_BW2 32768
#define OFF_BW3 36864
#define OFF_NW0 40960
#define OFF_NW2 81920
#define OFF_NW4 147456
#define OFF_NW6 253952
#define OFF_NW8 319488
#define WT_TOTAL 323584

// ---- MFMA helpers (16x16x32 f16; layouts per cdna_hip_programming.md §3) ---
// A frag: A[m=lane&15][k=(lane>>4)*8 + j], contiguous 8 halves.
// B frag: B[k=(lane>>4)*8 + j][n=lane&15]  == W^T[n][k] contiguous 8 halves.
// C/D:    col=lane&15, row=(lane>>4)*4 + reg.

template<int NT, int KT>
__device__ __forceinline__ void accum_panel(floatx4* acc,
                                            const unsigned short* ldsA, int strideA,
                                            const unsigned short* wt, int kpadW, int koffW) {
  const int lane = threadIdx.x & 63;
  const int nh = lane & 15, q = lane >> 4;
#pragma unroll
  for (int s = 0; s < KT; ++s) {
    half8 a = *reinterpret_cast<const half8*>(ldsA + nh * strideA + s * 32 + q * 8);
#pragma unroll
    for (int j = 0; j < NT; ++j) {
      half8 b = *reinterpret_cast<const half8*>(wt + (size_t)(j * 16 + nh) * kpadW + koffW + s * 32 + q * 8);
      acc[j] = __builtin_amdgcn_mfma_f32_16x16x32_f16(a, b, acc[j], 0, 0, 0);
    }
  }
}

template<int NT>
__device__ __forceinline__ void zero_acc(floatx4* acc) {
  floatx4 z = {0.f, 0.f, 0.f, 0.f};
#pragma unroll
  for (int j = 0; j < NT; ++j) acc[j] = z;
}

template<int NT>
__device__ __forceinline__ void epi_lds(const floatx4* acc, unsigned short* ldsOut,
                                        int strideO, int colOff, const float* bias, bool doRelu) {
  const int lane = threadIdx.x & 63;
  const int nh = lane & 15, q = lane >> 4;
#pragma unroll
  for (int j = 0; j < NT; ++j) {
    float bv = bias[j * 16 + nh];
#pragma unroll
    for (int r = 0; r < 4; ++r) {
      float v = acc[j][r] + bv;
      if (doRelu) v = fmaxf(v, 0.f);
      ldsOut[(q * 4 + r) * strideO + colOff + j * 16 + nh] = f2h(v);
    }
  }
}

// ---- kernel 1: weight transpose/cast + scalar output -----------------------
struct PrepArgs { const float* src[12]; };

__global__ __launch_bounds__(256) void prep_k(PrepArgs a, unsigned short* wt,
                                              float* outM, float Mval) {
  int gid = blockIdx.x * 256 + threadIdx.x;
  if (gid == 0) *outM = Mval;
  if (gid >= WT_TOTAL) return;
  int L = 0;
  while (gid >= T_OFF[L + 1]) ++L;
  int local = gid - T_OFF[L];
  int kp = T_KP[L];
  int n = local / kp;
  int k = local - n * kp;
  float v = 0.f;
  if (k < T_KS[L] && n < T_NS[L]) v = a.src[L][(size_t)k * T_NS[L] + n];
  wt[gid] = f2h(v);
}

// ---- kernel 2: voxel branch (gather -> 63->128->64 MLP) --------------------
__global__ __launch_bounds__(256) void voxel_k(const float* __restrict__ x,
                                               const int* __restrict__ inds,
                                               const unsigned short* __restrict__ wt,
                                               const float* __restrict__ ub1,
                                               const float* __restrict__ ub2,
                                               unsigned short* __restrict__ vout, int M) {
  __shared__ unsigned short lds[4 * 3328];
  const int wave = threadIdx.x >> 6, lane = threadIdx.x & 63;
  unsigned short* bufV = lds + wave * 3328;   // [16][72]
  unsigned short* bufU = bufV + 1152;         // [16][136]
  const int v0 = blockIdx.x * 64 + wave * 16;

  for (int idx = lane; idx < 16 * 64; idx += 64) {
    int p = idx >> 6, c = idx & 63;
    int v = v0 + p;
    float val = 0.f;
    if (v < M && c < 63) val = x[(size_t)inds[v] * X_STRIDE + c];
    bufV[p * 72 + c] = f2h(val);
  }

  floatx4 acc8[8];
  zero_acc<8>(acc8);
  accum_panel<8, 2>(acc8, bufV, 72, wt + OFF_UW1, 64, 0);
  epi_lds<8>(acc8, bufU, 136, 0, ub1, true);

  floatx4 acc4[4];
  zero_acc<4>(acc4);
  accum_panel<4, 4>(acc4, bufU, 136, wt + OFF_UW2, 128, 0);

  const int nh = lane & 15, q = lane >> 4;
#pragma unroll
  for (int j = 0; j < 4; ++j) {
    float bv = ub2[j * 16 + nh];
#pragma unroll
    for (int r = 0; r < 4; ++r) {
      int v = v0 + q * 4 + r;
      if (v < M) vout[(size_t)v * 64 + j * 16 + nh] = f2h(acc4[j][r] + bv);
    }
  }
}

// ---- kernel 3: fused per-point pipeline ------------------------------------
struct MainArgs {
  const float* x;
  const int* invmap;
  const unsigned short* wt;
  const unsigned short* vout;
  float* out;
  const float* fb1; const float* fb2;
  const float* bb1; const float* bb2; const float* bb3;
  const float* nb0; const float* nb2; const float* nb4; const float* nb6; const float* nb8;
};

__global__ __launch_bounds__(256, 2) void main_k(MainArgs a) {
  // per-wave LDS (elems): bufX 16x168, bufA 16x136, bufB 16x72, bufH 16x264
  __shared__ unsigned short lds[4 * 10240];
  const int wave = threadIdx.x >> 6, lane = threadIdx.x & 63;
  unsigned short* bufX = lds + wave * 10240;
  unsigned short* bufA = bufX + 16 * 168;
  unsigned short* bufB = bufA + 16 * 136;
  unsigned short* bufH = bufB + 16 * 72;
  const int p0 = blockIdx.x * 64 + wave * 16;

  // stage x[:, :76] -> bufX cols [0,76)
  for (int idx = lane; idx < 16 * 76; idx += 64) {
    int p = idx / 76, c = idx - p * 76;
    bufX[p * 168 + c] = f2h(a.x[(size_t)(p0 + p) * X_STRIDE + c]);
  }
  // zero bufX cols [140,168)
  for (int idx = lane; idx < 16 * 28; idx += 64) {
    int p = idx / 28, c = idx - p * 28;
    bufX[p * 168 + 140 + c] = 0;
  }
  // gather pcd (vout[invmap]) -> bufA cols [64,128)
  {
    int p = lane >> 4;
    const int c4 = lane & 15;
#pragma unroll
    for (int it = 0; it < 4; ++it, p += 4) {
      int r = a.invmap[p0 + p];
      *reinterpret_cast<ushort4v*>(bufA + p * 136 + 64 + c4 * 4) =
          *reinterpret_cast<const ushort4v*>(a.vout + (size_t)r * 64 + c4 * 4);
    }
  }
  __syncthreads();

  floatx4 acc4[4];
  floatx4 acc16[16];

  // front L1: pe(64) -> 64, relu   -> bufB
  zero_acc<4>(acc4);
  accum_panel<4, 2>(acc4, bufX, 168, a.wt + OFF_FW1, 64, 0);
  epi_lds<4>(acc4, bufB, 72, 0, a.fb1, true);
  __syncthreads();
  // front L2: 64 -> 64             -> bufA cols [0,64)
  zero_acc<4>(acc4);
  accum_panel<4, 2>(acc4, bufB, 72, a.wt + OFF_FW2, 64, 0);
  epi_lds<4>(acc4, bufA, 136, 0, a.fb2, false);
  __syncthreads();
  // b1: [front|pcd](128) -> 64, relu -> bufB
  zero_acc<4>(acc4);
  accum_panel<4, 4>(acc4, bufA, 136, a.wt + OFF_BW1, 128, 0);
  epi_lds<4>(acc4, bufB, 72, 0, a.bb1, true);
  __syncthreads();
  // b2: 64 -> 64, relu (in place bufB; acc fully computed before stores)
  zero_acc<4>(acc4);
  accum_panel<4, 2>(acc4, bufB, 72, a.wt + OFF_BW2, 64, 0);
  epi_lds<4>(acc4, bufB, 72, 0, a.bb2, true);
  __syncthreads();
  // b3: 64 -> 64 (back) -> bufX cols [76,140)
  zero_acc<4>(acc4);
  accum_panel<4, 2>(acc4, bufB, 72, a.wt + OFF_BW3, 64, 0);
  epi_lds<4>(acc4, bufX, 168, 76, a.bb3, false);
  __syncthreads();
  // n0: xx(160) -> 256, relu -> bufH
  zero_acc<16>(acc16);
  accum_panel<16, 5>(acc16, bufX, 168, a.wt + OFF_NW0, 160, 0);
  epi_lds<16>(acc16, bufH, 264, 0, a.nb0, true);
  __syncthreads();
  // n2: 256 -> 256, relu (in place bufH)
  zero_acc<16>(acc16);
  accum_panel<16, 8>(acc16, bufH, 264, a.wt + OFF_NW2, 256, 0);
  epi_lds<16>(acc16, bufH, 264, 0, a.nb2, true);
  __syncthreads();
  // n4: [h(256)|xx(140)] -> 256, relu (two panels into nw4^T, in place bufH)
  zero_acc<16>(acc16);
  accum_panel<16, 8>(acc16, bufH, 264, a.wt + OFF_NW4, 416, 0);
  accum_panel<16, 5>(acc16, bufX, 168, a.wt + OFF_NW4, 416, 256);
  epi_lds<16>(acc16, bufH, 264, 0, a.nb4, true);
  __syncthreads();
  // n6: 256 -> 256, relu (in place bufH)
  zero_acc<16>(acc16);
  accum_panel<16, 8>(acc16, bufH, 264, a.wt + OFF_NW6, 256, 0);
  epi_lds<16>(acc16, bufH, 264, 0, a.nb6, true);
  __syncthreads();
  // n8: 256 -> 12, direct to global
  zero_acc<1>(acc4);
  accum_panel<1, 8>(acc4, bufH, 264, a.wt + OFF_NW8, 256, 0);
  {
    const int nh = lane & 15, q = lane >> 4;
    if (nh < 12) {
      float bv = a.nb8[nh];
#pragma unroll
      for (int r = 0; r < 4; ++r) {
        a.out[(size_t)(p0 + q * 4 + r) * 12 + nh] = acc4[0][r] + bv;
      }
    }
  }
}

// ---- launch ----------------------------------------------------------------
extern "C" void kernel_launch(void* const* d_in, const int* in_sizes, int n_in,
                              void* d_out, int out_size, void* d_ws, size_t ws_size,
                              hipStream_t stream) {
  const float* x      = (const float*)d_in[0];
  const int*   inds   = (const int*)d_in[1];
  const int*   invmap = (const int*)d_in[2];
  const int M = in_sizes[1];

  unsigned short* wt   = (unsigned short*)d_ws;                       // 647 KB
  unsigned short* vout = (unsigned short*)((char*)d_ws + (1 << 20));  // M*64*2 (~14.4 MB)

  PrepArgs pa;
  pa.src[0]  = (const float*)d_in[3];   // fw1
  pa.src[1]  = (const float*)d_in[5];   // fw2
  pa.src[2]  = (const float*)d_in[7];   // uw1
  pa.src[3]  = (const float*)d_in[9];   // uw2
  pa.src[4]  = (const float*)d_in[11];  // bw1
  pa.src[5]  = (const float*)d_in[13];  // bw2
  pa.src[6]  = (const float*)d_in[15];  // bw3
  pa.src[7]  = (const float*)d_in[17];  // nw0
  pa.src[8]  = (const float*)d_in[19];  // nw2
  pa.src[9]  = (const float*)d_in[21];  // nw4
  pa.src[10] = (const float*)d_in[23];  // nw6
  pa.src[11] = (const float*)d_in[25];  // nw8

  float* outM = (float*)d_out + (size_t)N_PTS * 12;
  prep_k<<<(WT_TOTAL + 255) / 256, 256, 0, stream>>>(pa, wt, outM, (float)M);

  voxel_k<<<(M + 63) / 64, 256, 0, stream>>>(x, inds, wt,
                                             (const float*)d_in[8],   // ub1
                                             (const float*)d_in[10],  // ub2
                                             vout, M);

  MainArgs ma;
  ma.x = x; ma.invmap = invmap; ma.wt = wt; ma.vout = vout; ma.out = (float*)d_out;
  ma.fb1 = (const float*)d_in[4];  ma.fb2 = (const float*)d_in[6];
  ma.bb1 = (const float*)d_in[12]; ma.bb2 = (const float*)d_in[14]; ma.bb3 = (const float*)d_in[16];
  ma.nb0 = (const float*)d_in[18]; ma.nb2 = (const float*)d_in[20];
  ma.nb4 = (const float*)d_in[22]; ma.nb6 = (const float*)d_in[24]; ma.nb8 = (const float*)d_in[26];
  main_k<<<N_PTS / 64, 256, 0, stream>>>(ma);
}

// Round 3
// 429.528 us; speedup vs baseline: 2.4851x; 2.4851x over previous
//
#include <hip/hip_runtime.h>

#define N_PTS 262144
#define X_STRIDE 79

using floatx4  = __attribute__((ext_vector_type(4))) float;
using half8    = __attribute__((ext_vector_type(8))) _Float16;
using ushort8v = __attribute__((ext_vector_type(8))) unsigned short;

__device__ __forceinline__ unsigned short f2h(float f) {
  _Float16 h = (_Float16)f;
  return __builtin_bit_cast(unsigned short, h);
}

// ---- weight table: FRAGMENT-MAJOR fp16 -------------------------------------
// For layer L with padded dims (KPAD, NP): fragment chunk for (j, s, lane) at
//   off + ((j*KT + s)*64 + lane)*8      (KT = KPAD/32)
// holds W^T[j*16 + (lane&15)][s*32 + (lane>>4)*8 + 0..7]  (zero outside K,N).
// A wave's B-load is 64 lanes x 16B CONTIGUOUS = one coalesced 1KB read.
// layer:        fw1 fw2 uw1 uw2 bw1 bw2 bw3 nw0 nw2 nw4 nw6 nw8
__device__ const int T_KS[12]  = {63, 64, 63,128,128, 64, 64,140,256,396,256,256};
__device__ const int T_NS[12]  = {64, 64,128, 64, 64, 64, 64,256,256,256,256, 12};
__device__ const int T_KP[12]  = {64, 64, 64,128,128, 64, 64,160,256,416,256,256};
__device__ const int T_OFF[13] = {0,4096,8192,16384,24576,32768,36864,40960,
                                  81920,147456,253952,319488,323584};
#define OFF_FW1 0
#define OFF_FW2 4096
#define OFF_UW1 8192
#define OFF_UW2 16384
#define OFF_BW1 24576
#define OFF_BW2 32768
#define OFF_BW3 36864
#define OFF_NW0 40960
#define OFF_NW2 81920
#define OFF_NW4 147456
#define OFF_NW6 253952
#define OFF_NW8 319488
#define WT_TOTAL 323584

// ---- MFMA accum: NJ output column-tiles x NM point-tiles -------------------
// A frag: A[m=lane&15][k=(lane>>4)*8+j] from LDS.
// B frag: fragment-major wt (coalesced). C/D: col=lane&15, row=(lane>>4)*4+reg.
template<int NJ, int NM>
__device__ __forceinline__ void accum2(floatx4 (&acc)[NJ][NM],
    const unsigned short* ldsA, int strideA, int mrow0,
    const unsigned short* wtL, int KTtot, int jg0,
    int sBegin, int sEnd, int sABase) {
  const int lane = threadIdx.x & 63;
  const int nh = lane & 15, q = lane >> 4;
#pragma unroll 2
  for (int s = sBegin; s < sEnd; ++s) {
    half8 a[NM];
#pragma unroll
    for (int m = 0; m < NM; ++m)
      a[m] = *reinterpret_cast<const half8*>(
          ldsA + (mrow0 + m * 16 + nh) * strideA + (s - sABase) * 32 + q * 8);
#pragma unroll
    for (int j = 0; j < NJ; ++j) {
      half8 b = *reinterpret_cast<const half8*>(
          wtL + (size_t)(((jg0 + j) * KTtot + s) * 64 + lane) * 8);
#pragma unroll
      for (int m = 0; m < NM; ++m)
        acc[j][m] = __builtin_amdgcn_mfma_f32_16x16x32_f16(a[m], b, acc[j][m], 0, 0, 0);
    }
  }
}

template<int NJ, int NM>
__device__ __forceinline__ void zero2(floatx4 (&acc)[NJ][NM]) {
  floatx4 z = {0.f, 0.f, 0.f, 0.f};
#pragma unroll
  for (int j = 0; j < NJ; ++j)
#pragma unroll
    for (int m = 0; m < NM; ++m) acc[j][m] = z;
}

template<int NJ, int NM>
__device__ __forceinline__ void epi2(const floatx4 (&acc)[NJ][NM],
    unsigned short* ldsOut, int strideO, int colOff, int mrow0,
    const float* bias, int biasBase, bool relu) {
  const int lane = threadIdx.x & 63;
  const int nh = lane & 15, q = lane >> 4;
#pragma unroll
  for (int j = 0; j < NJ; ++j) {
    float bv = bias[biasBase + j * 16 + nh];
#pragma unroll
    for (int m = 0; m < NM; ++m)
#pragma unroll
      for (int r = 0; r < 4; ++r) {
        float v = acc[j][m][r] + bv;
        if (relu) v = fmaxf(v, 0.f);
        ldsOut[(mrow0 + m * 16 + q * 4 + r) * strideO + colOff + j * 16 + nh] = f2h(v);
      }
  }
}

// ---- kernel 1: weight repack (frag-major) + scalar output ------------------
struct PrepArgs { const float* src[12]; };

__global__ __launch_bounds__(256) void prep_k(PrepArgs a, unsigned short* wt,
                                              float* outM, float Mval) {
  int chunk = blockIdx.x * 256 + threadIdx.x;  // one thread per 8-half chunk
  if (chunk == 0) *outM = Mval;
  if (chunk >= WT_TOTAL / 8) return;
  int gid = chunk * 8;
  int L = 0;
  while (gid >= T_OFF[L + 1]) ++L;
  int local = chunk - T_OFF[L] / 8;
  int lane = local & 63;
  int t = local >> 6;
  int KT = T_KP[L] >> 5;
  int s = t % KT, j = t / KT;
  int nh = lane & 15, q = lane >> 4;
  int n = j * 16 + nh;
  int k0 = s * 32 + q * 8;
  const float* src = a.src[L];
  int K = T_KS[L], Nn = T_NS[L];
  ushort8v o;
#pragma unroll
  for (int i = 0; i < 8; ++i) {
    int k = k0 + i;
    float v = (k < K && n < Nn) ? src[(size_t)k * Nn + n] : 0.f;
    o[i] = f2h(v);
  }
  *reinterpret_cast<ushort8v*>(wt + gid) = o;
}

// ---- kernel 2: voxel branch, 64 voxels/block, N-split over 4 waves ---------
__global__ __launch_bounds__(256, 3) void voxel_k(const float* __restrict__ x,
                                                  const int* __restrict__ inds,
                                                  const unsigned short* __restrict__ wt,
                                                  const float* __restrict__ ub1,
                                                  const float* __restrict__ ub2,
                                                  unsigned short* __restrict__ vout, int M) {
  __shared__ unsigned short bufV[64 * 72];
  __shared__ unsigned short bufU[64 * 136];
  const int wave = threadIdx.x >> 6, lane = threadIdx.x & 63;
  const int nh = lane & 15, q = lane >> 4;
  const int v0 = blockIdx.x * 64;

  for (int idx = threadIdx.x; idx < 64 * 64; idx += 256) {
    int p = idx >> 6, c = idx & 63;
    int v = v0 + p;
    float val = 0.f;
    if (v < M && c < 63) val = x[(size_t)inds[v] * X_STRIDE + c];
    bufV[p * 72 + c] = f2h(val);
  }
  __syncthreads();

  floatx4 acc2[2][4];
  zero2<2, 4>(acc2);
  accum2<2, 4>(acc2, bufV, 72, 0, wt + OFF_UW1, 2, wave * 2, 0, 2, 0);
  epi2<2, 4>(acc2, bufU, 136, wave * 32, 0, ub1, wave * 32, true);
  __syncthreads();

  floatx4 acc1[1][4];
  zero2<1, 4>(acc1);
  accum2<1, 4>(acc1, bufU, 136, 0, wt + OFF_UW2, 4, wave, 0, 4, 0);
  float bv = ub2[wave * 16 + nh];
#pragma unroll
  for (int m = 0; m < 4; ++m)
#pragma unroll
    for (int r = 0; r < 4; ++r) {
      int v = v0 + m * 16 + q * 4 + r;
      if (v < M) vout[(size_t)v * 64 + wave * 16 + nh] = f2h(acc1[0][m][r] + bv);
    }
}

// ---- kernel 3: fused per-point pipeline, 64 pts/block ----------------------
// LDS: bufX[64][160] (x cols0..75 | back 76..139 | zeros), reg2[64][264 stride]
// reg2 column regions: [0:64) front / [64:128) pcd / [128:192) t1 / [192:256) t2
struct MainArgs {
  const float* x;
  const int* invmap;
  const unsigned short* wt;
  const unsigned short* vout;
  float* out;
  const float* fb1; const float* fb2;
  const float* bb1; const float* bb2; const float* bb3;
  const float* nb0; const float* nb2; const float* nb4; const float* nb6; const float* nb8;
};

__global__ __launch_bounds__(256, 3) void main_k(MainArgs a) {
  __shared__ unsigned short bufX[64 * 160];
  __shared__ unsigned short reg2[64 * 264];
  const int wave = threadIdx.x >> 6, lane = threadIdx.x & 63;
  const int nh = lane & 15, q = lane >> 4;
  const int p0 = blockIdx.x * 64;

  // stage x[:, :76] -> bufX cols [0,76)
  for (int idx = threadIdx.x; idx < 64 * 76; idx += 256) {
    int p = idx / 76, c = idx - p * 76;
    bufX[p * 160 + c] = f2h(a.x[(size_t)(p0 + p) * X_STRIDE + c]);
  }
  // zero bufX cols [140,160)
  for (int idx = threadIdx.x; idx < 64 * 20; idx += 256) {
    int p = idx / 20, c = idx - p * 20;
    bufX[p * 160 + 140 + c] = 0;
  }
  // gather pcd -> reg2 cols [64,128)
  for (int idx = threadIdx.x; idx < 64 * 8; idx += 256) {
    int p = idx >> 3, c = (idx & 7) * 8;
    int r = a.invmap[p0 + p];
    *reinterpret_cast<ushort8v*>(reg2 + p * 264 + 64 + c) =
        *reinterpret_cast<const ushort8v*>(a.vout + (size_t)r * 64 + c);
  }
  __syncthreads();

  floatx4 acc1[1][4];
  floatx4 acc4[4][4];

  // fw1: pe(k<63 of bufX) -> 64 relu -> reg2[128:192)
  zero2<1, 4>(acc1);
  accum2<1, 4>(acc1, bufX, 160, 0, a.wt + OFF_FW1, 2, wave, 0, 2, 0);
  epi2<1, 4>(acc1, reg2, 264, 128 + wave * 16, 0, a.fb1, wave * 16, true);
  __syncthreads();
  // fw2: -> front, reg2[0:64)
  zero2<1, 4>(acc1);
  accum2<1, 4>(acc1, reg2 + 128, 264, 0, a.wt + OFF_FW2, 2, wave, 0, 2, 0);
  epi2<1, 4>(acc1, reg2, 264, 0 + wave * 16, 0, a.fb2, wave * 16, false);
  __syncthreads();
  // bw1: [front|pcd](128) -> 64 relu -> reg2[128:192)
  zero2<1, 4>(acc1);
  accum2<1, 4>(acc1, reg2, 264, 0, a.wt + OFF_BW1, 4, wave, 0, 4, 0);
  epi2<1, 4>(acc1, reg2, 264, 128 + wave * 16, 0, a.bb1, wave * 16, true);
  __syncthreads();
  // bw2: -> 64 relu -> reg2[192:256)
  zero2<1, 4>(acc1);
  accum2<1, 4>(acc1, reg2 + 128, 264, 0, a.wt + OFF_BW2, 2, wave, 0, 2, 0);
  epi2<1, 4>(acc1, reg2, 264, 192 + wave * 16, 0, a.bb2, wave * 16, true);
  __syncthreads();
  // bw3: -> back -> bufX cols [76,140)
  zero2<1, 4>(acc1);
  accum2<1, 4>(acc1, reg2 + 192, 264, 0, a.wt + OFF_BW3, 2, wave, 0, 2, 0);
  epi2<1, 4>(acc1, bufX, 160, 76 + wave * 16, 0, a.bb3, wave * 16, false);
  __syncthreads();
  // n0: xx(160) -> 256 relu -> reg2[0:256)
  zero2<4, 4>(acc4);
  accum2<4, 4>(acc4, bufX, 160, 0, a.wt + OFF_NW0, 5, wave * 4, 0, 5, 0);
  epi2<4, 4>(acc4, reg2, 264, wave * 64, 0, a.nb0, wave * 64, true);
  __syncthreads();
  // n2: 256 -> 256 relu, in-place (barrier between read and write)
  zero2<4, 4>(acc4);
  accum2<4, 4>(acc4, reg2, 264, 0, a.wt + OFF_NW2, 8, wave * 4, 0, 8, 0);
  __syncthreads();
  epi2<4, 4>(acc4, reg2, 264, wave * 64, 0, a.nb2, wave * 64, true);
  __syncthreads();
  // n4: [h(256)|xx(140+pad)] -> 256 relu, in-place
  zero2<4, 4>(acc4);
  accum2<4, 4>(acc4, reg2, 264, 0, a.wt + OFF_NW4, 13, wave * 4, 0, 8, 0);
  accum2<4, 4>(acc4, bufX, 160, 0, a.wt + OFF_NW4, 13, wave * 4, 8, 13, 8);
  __syncthreads();
  epi2<4, 4>(acc4, reg2, 264, wave * 64, 0, a.nb4, wave * 64, true);
  __syncthreads();
  // n6: 256 -> 256 relu, in-place
  zero2<4, 4>(acc4);
  accum2<4, 4>(acc4, reg2, 264, 0, a.wt + OFF_NW6, 8, wave * 4, 0, 8, 0);
  __syncthreads();
  epi2<4, 4>(acc4, reg2, 264, wave * 64, 0, a.nb6, wave * 64, true);
  __syncthreads();
  // n8: 256 -> 12, each wave one m-tile, direct global store
  floatx4 accO[1][1];
  accO[0][0] = floatx4{0.f, 0.f, 0.f, 0.f};
  accum2<1, 1>(accO, reg2, 264, wave * 16, a.wt + OFF_NW8, 8, 0, 0, 8, 0);
  if (nh < 12) {
    float bv = a.nb8[nh];
#pragma unroll
    for (int r = 0; r < 4; ++r)
      a.out[(size_t)(p0 + wave * 16 + q * 4 + r) * 12 + nh] = accO[0][0][r] + bv;
  }
}

// ---- launch ----------------------------------------------------------------
extern "C" void kernel_launch(void* const* d_in, const int* in_sizes, int n_in,
                              void* d_out, int out_size, void* d_ws, size_t ws_size,
                              hipStream_t stream) {
  const float* x      = (const float*)d_in[0];
  const int*   inds   = (const int*)d_in[1];
  const int*   invmap = (const int*)d_in[2];
  const int M = in_sizes[1];

  unsigned short* wt   = (unsigned short*)d_ws;                       // 647 KB
  unsigned short* vout = (unsigned short*)((char*)d_ws + (1 << 20));  // M*64*2

  PrepArgs pa;
  pa.src[0]  = (const float*)d_in[3];   // fw1
  pa.src[1]  = (const float*)d_in[5];   // fw2
  pa.src[2]  = (const float*)d_in[7];   // uw1
  pa.src[3]  = (const float*)d_in[9];   // uw2
  pa.src[4]  = (const float*)d_in[11];  // bw1
  pa.src[5]  = (const float*)d_in[13];  // bw2
  pa.src[6]  = (const float*)d_in[15];  // bw3
  pa.src[7]  = (const float*)d_in[17];  // nw0
  pa.src[8]  = (const float*)d_in[19];  // nw2
  pa.src[9]  = (const float*)d_in[21];  // nw4
  pa.src[10] = (const float*)d_in[23];  // nw6
  pa.src[11] = (const float*)d_in[25];  // nw8

  float* outM = (float*)d_out + (size_t)N_PTS * 12;
  prep_k<<<(WT_TOTAL / 8 + 255) / 256, 256, 0, stream>>>(pa, wt, outM, (float)M);

  voxel_k<<<(M + 63) / 64, 256, 0, stream>>>(x, inds, wt,
                                             (const float*)d_in[8],   // ub1
                                             (const float*)d_in[10],  // ub2
                                             vout, M);

  MainArgs ma;
  ma.x = x; ma.invmap = invmap; ma.wt = wt; ma.vout = vout; ma.out = (float*)d_out;
  ma.fb1 = (const float*)d_in[4];  ma.fb2 = (const float*)d_in[6];
  ma.bb1 = (const float*)d_in[12]; ma.bb2 = (const float*)d_in[14]; ma.bb3 = (const float*)d_in[16];
  ma.nb0 = (const float*)d_in[18]; ma.nb2 = (const float*)d_in[20];
  ma.nb4 = (const float*)d_in[22]; ma.nb6 = (const float*)d_in[24]; ma.nb8 = (const float*)d_in[26];
  main_k<<<N_PTS / 64, 256, 0, stream>>>(ma);
}

// Round 4
// 416.233 us; speedup vs baseline: 2.5645x; 1.0319x over previous
//
#include <hip/hip_runtime.h>

#define N_PTS 262144
#define X_STRIDE 79

using floatx4  = __attribute__((ext_vector_type(4))) float;
using half8    = __attribute__((ext_vector_type(8))) _Float16;
using ushort4v = __attribute__((ext_vector_type(4))) unsigned short;
using ushort8v = __attribute__((ext_vector_type(8))) unsigned short;

__device__ __forceinline__ unsigned short f2h(float f) {
  _Float16 h = (_Float16)f;
  return __builtin_bit_cast(unsigned short, h);
}

// ---- weight table: FRAGMENT-MAJOR fp16 (used as MFMA *A* operand) ----------
// chunk (j, s, lane) at off + ((j*KT + s)*64 + lane)*8 holds
// W^T[j*16 + (lane&15)][s*32 + (lane>>4)*8 + 0..7]  (zero outside K,N).
// A-frag layout A[m][k]: m=lane&15, k=(lane>>4)*8+j -> identical mapping.
// layer:        fw1 fw2 uw1 uw2 bw1 bw2 bw3 nw0 nw2 nw4 nw6 nw8
__device__ const int T_KS[12]  = {63, 64, 63,128,128, 64, 64,140,256,396,256,256};
__device__ const int T_NS[12]  = {64, 64,128, 64, 64, 64, 64,256,256,256,256, 12};
__device__ const int T_KP[12]  = {64, 64, 64,128,128, 64, 64,160,256,416,256,256};
__device__ const int T_OFF[13] = {0,4096,8192,16384,24576,32768,36864,40960,
                                  81920,147456,253952,319488,323584};
#define OFF_FW1 0
#define OFF_FW2 4096
#define OFF_UW1 8192
#define OFF_UW2 16384
#define OFF_BW1 24576
#define OFF_BW2 32768
#define OFF_BW3 36864
#define OFF_NW0 40960
#define OFF_NW2 81920
#define OFF_NW4 147456
#define OFF_NW6 253952
#define OFF_NW8 319488
#define WT_TOTAL 323584

// ---- MFMA accum (FLIPPED): D = W^T_tile(A) x X^T_tile(B) -------------------
// acc[j][m]: j = feature tile (16 wide), m = point tile (16 pts).
// B-frag (activation): B[k][pt]: pt=lane&15, k=(lane>>4)*8+j -> LDS row-major
//   [point][feature] read, contiguous 16B per lane (same addressing as before).
// D: col = point = lane&15, row = feature = (lane>>4)*4 + reg  -> per-lane
//   4 CONSECUTIVE features for one point => packed b64 epilogue stores.
template<int NJ, int NM>
__device__ __forceinline__ void accum2(floatx4 (&acc)[NJ][NM],
    const unsigned short* ldsB, int strideB, int mrow0,
    const unsigned short* wtL, int KTtot, int jg0,
    int sBegin, int sEnd, int sBBase) {
  const int lane = threadIdx.x & 63;
  const int nh = lane & 15, q = lane >> 4;
#pragma unroll 2
  for (int s = sBegin; s < sEnd; ++s) {
    half8 b[NM];
#pragma unroll
    for (int m = 0; m < NM; ++m)
      b[m] = *reinterpret_cast<const half8*>(
          ldsB + (mrow0 + m * 16 + nh) * strideB + (s - sBBase) * 32 + q * 8);
#pragma unroll
    for (int j = 0; j < NJ; ++j) {
      half8 w = *reinterpret_cast<const half8*>(
          wtL + (size_t)(((jg0 + j) * KTtot + s) * 64 + lane) * 8);
#pragma unroll
      for (int m = 0; m < NM; ++m)
        acc[j][m] = __builtin_amdgcn_mfma_f32_16x16x32_f16(w, b[m], acc[j][m], 0, 0, 0);
    }
  }
}

template<int NJ, int NM>
__device__ __forceinline__ void zero2(floatx4 (&acc)[NJ][NM]) {
  floatx4 z = {0.f, 0.f, 0.f, 0.f};
#pragma unroll
  for (int j = 0; j < NJ; ++j)
#pragma unroll
    for (int m = 0; m < NM; ++m) acc[j][m] = z;
}

// epilogue: one ds_write_b64 per (j,m) tile; bias as float4.
template<int NJ, int NM>
__device__ __forceinline__ void epi2(const floatx4 (&acc)[NJ][NM],
    unsigned short* ldsOut, int strideO, int colOff, int mrow0,
    const float* bias, int biasBase, bool relu) {
  const int lane = threadIdx.x & 63;
  const int nh = lane & 15, q = lane >> 4;
#pragma unroll
  for (int j = 0; j < NJ; ++j) {
    floatx4 b4 = *reinterpret_cast<const floatx4*>(bias + biasBase + j * 16 + q * 4);
#pragma unroll
    for (int m = 0; m < NM; ++m) {
      ushort4v h;
#pragma unroll
      for (int r = 0; r < 4; ++r) {
        float v = acc[j][m][r] + b4[r];
        if (relu) v = fmaxf(v, 0.f);
        h[r] = f2h(v);
      }
      *reinterpret_cast<ushort4v*>(
          ldsOut + (mrow0 + m * 16 + nh) * strideO + colOff + j * 16 + q * 4) = h;
    }
  }
}

// ---- kernel 1: weight repack (frag-major) + scalar output ------------------
struct PrepArgs { const float* src[12]; };

__global__ __launch_bounds__(256) void prep_k(PrepArgs a, unsigned short* wt,
                                              float* outM, float Mval) {
  int chunk = blockIdx.x * 256 + threadIdx.x;  // one thread per 8-half chunk
  if (chunk == 0) *outM = Mval;
  if (chunk >= WT_TOTAL / 8) return;
  int gid = chunk * 8;
  int L = 0;
  while (gid >= T_OFF[L + 1]) ++L;
  int local = chunk - T_OFF[L] / 8;
  int lane = local & 63;
  int t = local >> 6;
  int KT = T_KP[L] >> 5;
  int s = t % KT, j = t / KT;
  int nh = lane & 15, q = lane >> 4;
  int n = j * 16 + nh;
  int k0 = s * 32 + q * 8;
  const float* src = a.src[L];
  int K = T_KS[L], Nn = T_NS[L];
  ushort8v o;
#pragma unroll
  for (int i = 0; i < 8; ++i) {
    int k = k0 + i;
    float v = (k < K && n < Nn) ? src[(size_t)k * Nn + n] : 0.f;
    o[i] = f2h(v);
  }
  *reinterpret_cast<ushort8v*>(wt + gid) = o;
}

// ---- kernel 2: voxel branch, 64 voxels/block, feature-split over 4 waves ---
__global__ __launch_bounds__(256, 3) void voxel_k(const float* __restrict__ x,
                                                  const int* __restrict__ inds,
                                                  const unsigned short* __restrict__ wt,
                                                  const float* __restrict__ ub1,
                                                  const float* __restrict__ ub2,
                                                  unsigned short* __restrict__ vout, int M) {
  __shared__ unsigned short bufV[64 * 72];
  __shared__ unsigned short bufU[64 * 136];
  const int wave = threadIdx.x >> 6, lane = threadIdx.x & 63;
  const int nh = lane & 15, q = lane >> 4;
  const int v0 = blockIdx.x * 64;

  for (int idx = threadIdx.x; idx < 64 * 64; idx += 256) {
    int p = idx >> 6, c = idx & 63;
    int v = v0 + p;
    float val = 0.f;
    if (v < M && c < 63) val = x[(size_t)inds[v] * X_STRIDE + c];
    bufV[p * 72 + c] = f2h(val);
  }
  __syncthreads();

  floatx4 acc2[2][4];
  zero2<2, 4>(acc2);
  accum2<2, 4>(acc2, bufV, 72, 0, wt + OFF_UW1, 2, wave * 2, 0, 2, 0);
  epi2<2, 4>(acc2, bufU, 136, wave * 32, 0, ub1, wave * 32, true);
  __syncthreads();

  floatx4 acc1[1][4];
  zero2<1, 4>(acc1);
  accum2<1, 4>(acc1, bufU, 136, 0, wt + OFF_UW2, 4, wave, 0, 4, 0);
  // D: col=voxel=nh(+m*16), row=feature=wave*16+q*4+r -> packed b64 stores
  floatx4 b4 = *reinterpret_cast<const floatx4*>(ub2 + wave * 16 + q * 4);
#pragma unroll
  for (int m = 0; m < 4; ++m) {
    int v = v0 + m * 16 + nh;
    if (v < M) {
      ushort4v h;
#pragma unroll
      for (int r = 0; r < 4; ++r) h[r] = f2h(acc1[0][m][r] + b4[r]);
      *reinterpret_cast<ushort4v*>(vout + (size_t)v * 64 + wave * 16 + q * 4) = h;
    }
  }
}

// ---- kernel 3: fused per-point pipeline, 64 pts/block ----------------------
// LDS rows = points. bufX[64][160]: x cols [0,76) | back [76,140) | zero pad.
// reg2[64][264]: front [0,64) / pcd [64,128) / t1 [128,192) / t2 [192,256)
struct MainArgs {
  const float* x;
  const int* invmap;
  const unsigned short* wt;
  const unsigned short* vout;
  float* out;
  const float* fb1; const float* fb2;
  const float* bb1; const float* bb2; const float* bb3;
  const float* nb0; const float* nb2; const float* nb4; const float* nb6; const float* nb8;
};

__global__ __launch_bounds__(256, 3) void main_k(MainArgs a) {
  __shared__ unsigned short bufX[64 * 160];
  __shared__ unsigned short reg2[64 * 264];
  const int wave = threadIdx.x >> 6, lane = threadIdx.x & 63;
  const int nh = lane & 15, q = lane >> 4;
  const int p0 = blockIdx.x * 64;

  // stage x[:, :76] -> bufX cols [0,76)
  for (int idx = threadIdx.x; idx < 64 * 76; idx += 256) {
    int p = idx / 76, c = idx - p * 76;
    bufX[p * 160 + c] = f2h(a.x[(size_t)(p0 + p) * X_STRIDE + c]);
  }
  // zero bufX cols [140,160)
  for (int idx = threadIdx.x; idx < 64 * 20; idx += 256) {
    int p = idx / 20, c = idx - p * 20;
    bufX[p * 160 + 140 + c] = 0;
  }
  // gather pcd -> reg2 cols [64,128)
  for (int idx = threadIdx.x; idx < 64 * 8; idx += 256) {
    int p = idx >> 3, c = (idx & 7) * 8;
    int r = a.invmap[p0 + p];
    *reinterpret_cast<ushort8v*>(reg2 + p * 264 + 64 + c) =
        *reinterpret_cast<const ushort8v*>(a.vout + (size_t)r * 64 + c);
  }
  __syncthreads();

  floatx4 acc1[1][4];
  floatx4 acc4[4][4];

  // fw1: pe -> 64 relu -> reg2[128:192)
  zero2<1, 4>(acc1);
  accum2<1, 4>(acc1, bufX, 160, 0, a.wt + OFF_FW1, 2, wave, 0, 2, 0);
  epi2<1, 4>(acc1, reg2, 264, 128 + wave * 16, 0, a.fb1, wave * 16, true);
  __syncthreads();
  // fw2: -> front, reg2[0:64)
  zero2<1, 4>(acc1);
  accum2<1, 4>(acc1, reg2 + 128, 264, 0, a.wt + OFF_FW2, 2, wave, 0, 2, 0);
  epi2<1, 4>(acc1, reg2, 264, 0 + wave * 16, 0, a.fb2, wave * 16, false);
  __syncthreads();
  // bw1: [front|pcd](128) -> 64 relu -> reg2[128:192)
  zero2<1, 4>(acc1);
  accum2<1, 4>(acc1, reg2, 264, 0, a.wt + OFF_BW1, 4, wave, 0, 4, 0);
  epi2<1, 4>(acc1, reg2, 264, 128 + wave * 16, 0, a.bb1, wave * 16, true);
  __syncthreads();
  // bw2: -> 64 relu -> reg2[192:256)
  zero2<1, 4>(acc1);
  accum2<1, 4>(acc1, reg2 + 128, 264, 0, a.wt + OFF_BW2, 2, wave, 0, 2, 0);
  epi2<1, 4>(acc1, reg2, 264, 192 + wave * 16, 0, a.bb2, wave * 16, true);
  __syncthreads();
  // bw3: -> back -> bufX cols [76,140)
  zero2<1, 4>(acc1);
  accum2<1, 4>(acc1, reg2 + 192, 264, 0, a.wt + OFF_BW3, 2, wave, 0, 2, 0);
  epi2<1, 4>(acc1, bufX, 160, 76 + wave * 16, 0, a.bb3, wave * 16, false);
  __syncthreads();
  // n0: xx(160) -> 256 relu -> reg2[0:256)
  zero2<4, 4>(acc4);
  accum2<4, 4>(acc4, bufX, 160, 0, a.wt + OFF_NW0, 5, wave * 4, 0, 5, 0);
  epi2<4, 4>(acc4, reg2, 264, wave * 64, 0, a.nb0, wave * 64, true);
  __syncthreads();
  // n2: 256 -> 256 relu, in-place (barrier between read and write)
  zero2<4, 4>(acc4);
  accum2<4, 4>(acc4, reg2, 264, 0, a.wt + OFF_NW2, 8, wave * 4, 0, 8, 0);
  __syncthreads();
  epi2<4, 4>(acc4, reg2, 264, wave * 64, 0, a.nb2, wave * 64, true);
  __syncthreads();
  // n4: [h(256)|xx(140+pad)] -> 256 relu, in-place
  zero2<4, 4>(acc4);
  accum2<4, 4>(acc4, reg2, 264, 0, a.wt + OFF_NW4, 13, wave * 4, 0, 8, 0);
  accum2<4, 4>(acc4, bufX, 160, 0, a.wt + OFF_NW4, 13, wave * 4, 8, 13, 8);
  __syncthreads();
  epi2<4, 4>(acc4, reg2, 264, wave * 64, 0, a.nb4, wave * 64, true);
  __syncthreads();
  // n6: 256 -> 256 relu, in-place
  zero2<4, 4>(acc4);
  accum2<4, 4>(acc4, reg2, 264, 0, a.wt + OFF_NW6, 8, wave * 4, 0, 8, 0);
  __syncthreads();
  epi2<4, 4>(acc4, reg2, 264, wave * 64, 0, a.nb6, wave * 64, true);
  __syncthreads();
  // n8: 256 -> 12; D rows = out channels (q*4+r, valid q<3), cols = points.
  floatx4 accO[1][1];
  accO[0][0] = floatx4{0.f, 0.f, 0.f, 0.f};
  accum2<1, 1>(accO, reg2, 264, wave * 16, a.wt + OFF_NW8, 8, 0, 0, 8, 0);
  if (q < 3) {
    floatx4 o;
#pragma unroll
    for (int r = 0; r < 4; ++r) o[r] = accO[0][0][r] + a.nb8[q * 4 + r];
    *reinterpret_cast<floatx4*>(a.out + (size_t)(p0 + wave * 16 + nh) * 12 + q * 4) = o;
  }
}

// ---- launch ----------------------------------------------------------------
extern "C" void kernel_launch(void* const* d_in, const int* in_sizes, int n_in,
                              void* d_out, int out_size, void* d_ws, size_t ws_size,
                              hipStream_t stream) {
  const float* x      = (const float*)d_in[0];
  const int*   inds   = (const int*)d_in[1];
  const int*   invmap = (const int*)d_in[2];
  const int M = in_sizes[1];

  unsigned short* wt   = (unsigned short*)d_ws;                       // 647 KB
  unsigned short* vout = (unsigned short*)((char*)d_ws + (1 << 20));  // M*64*2

  PrepArgs pa;
  pa.src[0]  = (const float*)d_in[3];   // fw1
  pa.src[1]  = (const float*)d_in[5];   // fw2
  pa.src[2]  = (const float*)d_in[7];   // uw1
  pa.src[3]  = (const float*)d_in[9];   // uw2
  pa.src[4]  = (const float*)d_in[11];  // bw1
  pa.src[5]  = (const float*)d_in[13];  // bw2
  pa.src[6]  = (const float*)d_in[15];  // bw3
  pa.src[7]  = (const float*)d_in[17];  // nw0
  pa.src[8]  = (const float*)d_in[19];  // nw2
  pa.src[9]  = (const float*)d_in[21];  // nw4
  pa.src[10] = (const float*)d_in[23];  // nw6
  pa.src[11] = (const float*)d_in[25];  // nw8

  float* outM = (float*)d_out + (size_t)N_PTS * 12;
  prep_k<<<(WT_TOTAL / 8 + 255) / 256, 256, 0, stream>>>(pa, wt, outM, (float)M);

  voxel_k<<<(M + 63) / 64, 256, 0, stream>>>(x, inds, wt,
                                             (const float*)d_in[8],   // ub1
                                             (const float*)d_in[10],  // ub2
                                             vout, M);

  MainArgs ma;
  ma.x = x; ma.invmap = invmap; ma.wt = wt; ma.vout = vout; ma.out = (float*)d_out;
  ma.fb1 = (const float*)d_in[4];  ma.fb2 = (const float*)d_in[6];
  ma.bb1 = (const float*)d_in[12]; ma.bb2 = (const float*)d_in[14]; ma.bb3 = (const float*)d_in[16];
  ma.nb0 = (const float*)d_in[18]; ma.nb2 = (const float*)d_in[20];
  ma.nb4 = (const float*)d_in[22]; ma.nb6 = (const float*)d_in[24]; ma.nb8 = (const float*)d_in[26];
  main_k<<<N_PTS / 64, 256, 0, stream>>>(ma);
}

// Round 5
// 396.239 us; speedup vs baseline: 2.6939x; 1.0505x over previous
//
#include <hip/hip_runtime.h>

#define N_PTS 262144
#define X_STRIDE 79

using floatx4   = __attribute__((ext_vector_type(4))) float;
using floatx16  = __attribute__((ext_vector_type(16))) float;
using half8     = __attribute__((ext_vector_type(8))) _Float16;
using ushort4v  = __attribute__((ext_vector_type(4))) unsigned short;
using ushort8v  = __attribute__((ext_vector_type(8))) unsigned short;

__device__ __forceinline__ unsigned short f2h(float f) {
  _Float16 h = (_Float16)f;
  return __builtin_bit_cast(unsigned short, h);
}

// ---- weight table: FRAGMENT-MAJOR fp16, 32x32x16 tiles (A operand) ---------
// Layers 0..10: chunk (j, s, lane) at off + ((j*KT + s)*64 + lane)*8 holds
//   W^T[j*32 + (lane&31)][s*16 + (lane>>5)*8 + 0..7], KT = KP/16.
// Layer 11 (nw8): 16x16x32 layout: W^T[j*16+(lane&15)][s*32+(lane>>4)*8+..], KT=KP/32.
// layer:        fw1 fw2 uw1 uw2 bw1 bw2 bw3 nw0 nw2 nw4 nw6 nw8
__device__ const int T_KS[12]  = {63, 64, 63,128,128, 64, 64,140,256,396,256,256};
__device__ const int T_NS[12]  = {64, 64,128, 64, 64, 64, 64,256,256,256,256, 12};
__device__ const int T_KP[12]  = {64, 64, 64,128,128, 64, 64,144,256,400,256,256};
__device__ const int T_OFF[13] = {0,4096,8192,16384,24576,32768,36864,40960,
                                  77824,143360,245760,311296,315392};
#define OFF_FW1 0
#define OFF_FW2 4096
#define OFF_UW1 8192
#define OFF_UW2 16384
#define OFF_BW1 24576
#define OFF_BW2 32768
#define OFF_BW3 36864
#define OFF_NW0 40960
#define OFF_NW2 77824
#define OFF_NW4 143360
#define OFF_NW6 245760
#define OFF_NW8 311296
#define WT_TOTAL 315392

// ---- 32x32x16 MFMA accum: D(features x points) = W^T(A) x X^T(B) -----------
// A frag: A[feat=lane&31][k=(lane>>5)*8+i]  (frag-major wt, contiguous 16B).
// B frag: B[k=(lane>>5)*8+i][pt=lane&31]  -> LDS row(point)-major 16B read.
// D: col=pt=lane&31, row=feat=(reg&3)+8*(reg>>2)+4*(lane>>5).
template<int NJ, int NM>
__device__ __forceinline__ void accum32(floatx16 (&acc)[NJ][NM],
    const unsigned short* ldsB, int strideB, int mrow0,
    const unsigned short* wtL, int KTtot, int jg0,
    int sBegin, int sEnd, int sBBase) {
  const int lane = threadIdx.x & 63;
  const int pr = lane & 31, h = lane >> 5;
#pragma unroll 2
  for (int s = sBegin; s < sEnd; ++s) {
    half8 b[NM];
#pragma unroll
    for (int m = 0; m < NM; ++m)
      b[m] = *reinterpret_cast<const half8*>(
          ldsB + (mrow0 + m * 32 + pr) * strideB + (s - sBBase) * 16 + h * 8);
#pragma unroll
    for (int j = 0; j < NJ; ++j) {
      half8 w = *reinterpret_cast<const half8*>(
          wtL + (size_t)(((jg0 + j) * KTtot + s) * 64 + lane) * 8);
#pragma unroll
      for (int m = 0; m < NM; ++m)
        acc[j][m] = __builtin_amdgcn_mfma_f32_32x32x16_f16(w, b[m], acc[j][m], 0, 0, 0);
    }
  }
}

template<int NJ, int NM>
__device__ __forceinline__ void zero32(floatx16 (&acc)[NJ][NM]) {
#pragma unroll
  for (int j = 0; j < NJ; ++j)
#pragma unroll
    for (int m = 0; m < NM; ++m)
#pragma unroll
      for (int r = 0; r < 16; ++r) acc[j][m][r] = 0.f;
}

// epilogue: 4 reg-groups per tile, each one packed ds_write_b64.
// feature of (j,g,h,r) = colOff + j*32 + g*8 + h*4 + r  (colOff includes jg0*32)
template<int NJ, int NM>
__device__ __forceinline__ void epi32(const floatx16 (&acc)[NJ][NM],
    unsigned short* ldsOut, int strideO, int colOff, int mrow0,
    const float* bias, int biasBase, bool relu) {
  const int lane = threadIdx.x & 63;
  const int pr = lane & 31, h = lane >> 5;
#pragma unroll
  for (int j = 0; j < NJ; ++j) {
#pragma unroll
    for (int g = 0; g < 4; ++g) {
      floatx4 b4 = *reinterpret_cast<const floatx4*>(bias + biasBase + j * 32 + g * 8 + h * 4);
#pragma unroll
      for (int m = 0; m < NM; ++m) {
        ushort4v hv;
#pragma unroll
        for (int r = 0; r < 4; ++r) {
          float v = acc[j][m][g * 4 + r] + b4[r];
          if (relu) v = fmaxf(v, 0.f);
          hv[r] = f2h(v);
        }
        *reinterpret_cast<ushort4v*>(
            ldsOut + (mrow0 + m * 32 + pr) * strideO + colOff + j * 32 + g * 8 + h * 4) = hv;
      }
    }
  }
}

// 16x16x32 path (kept for nw8 only)
__device__ __forceinline__ void accum16(floatx4& acc,
    const unsigned short* ldsB, int strideB, int mrow0,
    const unsigned short* wtL, int KTtot, int sEnd) {
  const int lane = threadIdx.x & 63;
  const int nh = lane & 15, q = lane >> 4;
#pragma unroll
  for (int s = 0; s < 8; ++s) {
    if (s >= sEnd) break;
    half8 b = *reinterpret_cast<const half8*>(
        ldsB + (mrow0 + nh) * strideB + s * 32 + q * 8);
    half8 w = *reinterpret_cast<const half8*>(
        wtL + (size_t)((s)*64 + lane) * 8);
    acc = __builtin_amdgcn_mfma_f32_16x16x32_f16(w, b, acc, 0, 0, 0);
  }
}

// ---- kernel 1: weight repack + scalar output -------------------------------
struct PrepArgs { const float* src[12]; };

__global__ __launch_bounds__(256) void prep_k(PrepArgs a, unsigned short* wt,
                                              float* outM, float Mval) {
  int chunk = blockIdx.x * 256 + threadIdx.x;  // one thread per 8-half chunk
  if (chunk == 0) *outM = Mval;
  if (chunk >= WT_TOTAL / 8) return;
  int gid = chunk * 8;
  int L = 0;
  while (gid >= T_OFF[L + 1]) ++L;
  int local = chunk - T_OFF[L] / 8;
  int lane = local & 63;
  int t = local >> 6;
  int n, k0;
  if (L < 11) {
    int KT = T_KP[L] >> 4;
    int s = t % KT, j = t / KT;
    n = j * 32 + (lane & 31);
    k0 = s * 16 + (lane >> 5) * 8;
  } else {
    int KT = T_KP[L] >> 5;
    int s = t % KT, j = t / KT;
    n = j * 16 + (lane & 15);
    k0 = s * 32 + (lane >> 4) * 8;
  }
  const float* src = a.src[L];
  int K = T_KS[L], Nn = T_NS[L];
  ushort8v o;
#pragma unroll
  for (int i = 0; i < 8; ++i) {
    int k = k0 + i;
    float v = (k < K && n < Nn) ? src[(size_t)k * Nn + n] : 0.f;
    o[i] = f2h(v);
  }
  *reinterpret_cast<ushort8v*>(wt + gid) = o;
}

// ---- kernel 2: voxel branch, 64 voxels/block -------------------------------
__global__ __launch_bounds__(256, 3) void voxel_k(const float* __restrict__ x,
                                                  const int* __restrict__ inds,
                                                  const unsigned short* __restrict__ wt,
                                                  const float* __restrict__ ub1,
                                                  const float* __restrict__ ub2,
                                                  unsigned short* __restrict__ vout, int M) {
  __shared__ unsigned short bufV[64 * 72];
  __shared__ unsigned short bufU[64 * 136];
  const int wave = threadIdx.x >> 6, lane = threadIdx.x & 63;
  const int pr = lane & 31, h = lane >> 5;
  const int v0 = blockIdx.x * 64;

  for (int idx = threadIdx.x; idx < 64 * 64; idx += 256) {
    int p = idx >> 6, c = idx & 63;
    int v = v0 + p;
    float val = 0.f;
    if (v < M && c < 63) val = x[(size_t)inds[v] * X_STRIDE + c];
    bufV[p * 72 + c] = f2h(val);
  }
  __syncthreads();

  // uw1: 63->128 relu. wave -> (jpair = wave&1 -> j {0,1}+2*(wave&1), m = wave>>1)
  {
    floatx16 acc[2][1];
    zero32<2, 1>(acc);
    int jg0 = (wave & 1) * 2, m0 = (wave >> 1) * 32;
    accum32<2, 1>(acc, bufV, 72, m0, wt + OFF_UW1, 4, jg0, 0, 4, 0);
    epi32<2, 1>(acc, bufU, 136, jg0 * 32, m0, ub1, jg0 * 32, true);
  }
  __syncthreads();

  // uw2: 128->64. wave -> (j = wave&1, m = wave>>1), direct global store
  {
    floatx16 acc[1][1];
    zero32<1, 1>(acc);
    int j = wave & 1, m0 = (wave >> 1) * 32;
    accum32<1, 1>(acc, bufU, 136, m0, wt + OFF_UW2, 8, j, 0, 8, 0);
    int v = v0 + m0 + pr;
    if (v < M) {
#pragma unroll
      for (int g = 0; g < 4; ++g) {
        floatx4 b4 = *reinterpret_cast<const floatx4*>(ub2 + j * 32 + g * 8 + h * 4);
        ushort4v hv;
#pragma unroll
        for (int r = 0; r < 4; ++r) hv[r] = f2h(acc[0][0][g * 4 + r] + b4[r]);
        *reinterpret_cast<ushort4v*>(vout + (size_t)v * 64 + j * 32 + g * 8 + h * 4) = hv;
      }
    }
  }
}

// ---- kernel 3: fused per-point pipeline, 64 pts/block ----------------------
// LDS rows = points. bufX[64][152]: x [0,76) | back [76,140) | zero [140,152).
// reg2[64][264]: front [0,64) / pcd [64,128) / t1 [128,192) / t2 [192,256)
struct MainArgs {
  const float* x;
  const int* invmap;
  const unsigned short* wt;
  const unsigned short* vout;
  float* out;
  const float* fb1; const float* fb2;
  const float* bb1; const float* bb2; const float* bb3;
  const float* nb0; const float* nb2; const float* nb4; const float* nb6; const float* nb8;
};

__global__ __launch_bounds__(256, 3) void main_k(MainArgs a) {
  __shared__ unsigned short bufX[64 * 152];
  __shared__ unsigned short reg2[64 * 264];
  const int wave = threadIdx.x >> 6, lane = threadIdx.x & 63;
  const int p0 = blockIdx.x * 64;

  // stage x[:, :76] -> bufX cols [0,76)
  for (int idx = threadIdx.x; idx < 64 * 76; idx += 256) {
    int p = idx / 76, c = idx - p * 76;
    bufX[p * 152 + c] = f2h(a.x[(size_t)(p0 + p) * X_STRIDE + c]);
  }
  // zero bufX cols [140,152)
  for (int idx = threadIdx.x; idx < 64 * 12; idx += 256) {
    int p = idx / 12, c = idx - p * 12;
    bufX[p * 152 + 140 + c] = 0;
  }
  // gather pcd -> reg2 cols [64,128)
  for (int idx = threadIdx.x; idx < 64 * 8; idx += 256) {
    int p = idx >> 3, c = (idx & 7) * 8;
    int r = a.invmap[p0 + p];
    *reinterpret_cast<ushort8v*>(reg2 + p * 264 + 64 + c) =
        *reinterpret_cast<const ushort8v*>(a.vout + (size_t)r * 64 + c);
  }
  __syncthreads();

  const int jw = wave & 1, mw = (wave >> 1) * 32;  // for 64-wide layers

  // fw1: pe -> 64 relu -> reg2 t1 [128,192)
  {
    floatx16 acc[1][1];
    zero32<1, 1>(acc);
    accum32<1, 1>(acc, bufX, 152, mw, a.wt + OFF_FW1, 4, jw, 0, 4, 0);
    epi32<1, 1>(acc, reg2, 264, 128 + jw * 32, mw, a.fb1, jw * 32, true);
  }
  __syncthreads();
  // fw2: t1 -> front [0,64)
  {
    floatx16 acc[1][1];
    zero32<1, 1>(acc);
    accum32<1, 1>(acc, reg2 + 128, 264, mw, a.wt + OFF_FW2, 4, jw, 0, 4, 0);
    epi32<1, 1>(acc, reg2, 264, jw * 32, mw, a.fb2, jw * 32, false);
  }
  __syncthreads();
  // bw1: [front|pcd](128) -> 64 relu -> t1
  {
    floatx16 acc[1][1];
    zero32<1, 1>(acc);
    accum32<1, 1>(acc, reg2, 264, mw, a.wt + OFF_BW1, 8, jw, 0, 8, 0);
    epi32<1, 1>(acc, reg2, 264, 128 + jw * 32, mw, a.bb1, jw * 32, true);
  }
  __syncthreads();
  // bw2: t1 -> 64 relu -> t2 [192,256)
  {
    floatx16 acc[1][1];
    zero32<1, 1>(acc);
    accum32<1, 1>(acc, reg2 + 128, 264, mw, a.wt + OFF_BW2, 4, jw, 0, 4, 0);
    epi32<1, 1>(acc, reg2, 264, 192 + jw * 32, mw, a.bb2, jw * 32, true);
  }
  __syncthreads();
  // bw3: t2 -> back -> bufX cols [76,140)
  {
    floatx16 acc[1][1];
    zero32<1, 1>(acc);
    accum32<1, 1>(acc, reg2 + 192, 264, mw, a.wt + OFF_BW3, 4, jw, 0, 4, 0);
    epi32<1, 1>(acc, bufX, 152, 76 + jw * 32, mw, a.bb3, jw * 32, false);
  }
  __syncthreads();

  // 256-wide: each wave NJ=2 (features wave*64..+64), NM=2 (all 64 pts)
  // n0: xx(144) -> 256 relu -> reg2[0:256)
  {
    floatx16 acc[2][2];
    zero32<2, 2>(acc);
    accum32<2, 2>(acc, bufX, 152, 0, a.wt + OFF_NW0, 9, wave * 2, 0, 9, 0);
    epi32<2, 2>(acc, reg2, 264, wave * 64, 0, a.nb0, wave * 64, true);
  }
  __syncthreads();
  // n2: 256 -> 256 relu, in-place
  {
    floatx16 acc[2][2];
    zero32<2, 2>(acc);
    accum32<2, 2>(acc, reg2, 264, 0, a.wt + OFF_NW2, 16, wave * 2, 0, 16, 0);
    __syncthreads();
    epi32<2, 2>(acc, reg2, 264, wave * 64, 0, a.nb2, wave * 64, true);
  }
  __syncthreads();
  // n4: [h(256)|xx(144)] -> 256 relu, in-place
  {
    floatx16 acc[2][2];
    zero32<2, 2>(acc);
    accum32<2, 2>(acc, reg2, 264, 0, a.wt + OFF_NW4, 25, wave * 2, 0, 16, 0);
    accum32<2, 2>(acc, bufX, 152, 0, a.wt + OFF_NW4, 25, wave * 2, 16, 25, 16);
    __syncthreads();
    epi32<2, 2>(acc, reg2, 264, wave * 64, 0, a.nb4, wave * 64, true);
  }
  __syncthreads();
  // n6: 256 -> 256 relu, in-place
  {
    floatx16 acc[2][2];
    zero32<2, 2>(acc);
    accum32<2, 2>(acc, reg2, 264, 0, a.wt + OFF_NW6, 16, wave * 2, 0, 16, 0);
    __syncthreads();
    epi32<2, 2>(acc, reg2, 264, wave * 64, 0, a.nb6, wave * 64, true);
  }
  __syncthreads();
  // n8: 256 -> 12 via 16x16x32; wave -> m-tile of 16 pts; direct global store
  {
    const int nh = lane & 15, q = lane >> 4;
    floatx4 acc = {0.f, 0.f, 0.f, 0.f};
    accum16(acc, reg2, 264, wave * 16, a.wt + OFF_NW8, 8, 8);
    if (q < 3) {
      floatx4 o;
#pragma unroll
      for (int r = 0; r < 4; ++r) o[r] = acc[r] + a.nb8[q * 4 + r];
      *reinterpret_cast<floatx4*>(a.out + (size_t)(p0 + wave * 16 + nh) * 12 + q * 4) = o;
    }
  }
}

// ---- launch ----------------------------------------------------------------
extern "C" void kernel_launch(void* const* d_in, const int* in_sizes, int n_in,
                              void* d_out, int out_size, void* d_ws, size_t ws_size,
                              hipStream_t stream) {
  const float* x      = (const float*)d_in[0];
  const int*   inds   = (const int*)d_in[1];
  const int*   invmap = (const int*)d_in[2];
  const int M = in_sizes[1];

  unsigned short* wt   = (unsigned short*)d_ws;                       // 631 KB
  unsigned short* vout = (unsigned short*)((char*)d_ws + (1 << 20));  // M*64*2

  PrepArgs pa;
  pa.src[0]  = (const float*)d_in[3];   // fw1
  pa.src[1]  = (const float*)d_in[5];   // fw2
  pa.src[2]  = (const float*)d_in[7];   // uw1
  pa.src[3]  = (const float*)d_in[9];   // uw2
  pa.src[4]  = (const float*)d_in[11];  // bw1
  pa.src[5]  = (const float*)d_in[13];  // bw2
  pa.src[6]  = (const float*)d_in[15];  // bw3
  pa.src[7]  = (const float*)d_in[17];  // nw0
  pa.src[8]  = (const float*)d_in[19];  // nw2
  pa.src[9]  = (const float*)d_in[21];  // nw4
  pa.src[10] = (const float*)d_in[23];  // nw6
  pa.src[11] = (const float*)d_in[25];  // nw8

  float* outM = (float*)d_out + (size_t)N_PTS * 12;
  prep_k<<<(WT_TOTAL / 8 + 255) / 256, 256, 0, stream>>>(pa, wt, outM, (float)M);

  voxel_k<<<(M + 63) / 64, 256, 0, stream>>>(x, inds, wt,
                                             (const float*)d_in[8],   // ub1
                                             (const float*)d_in[10],  // ub2
                                             vout, M);

  MainArgs ma;
  ma.x = x; ma.invmap = invmap; ma.wt = wt; ma.vout = vout; ma.out = (float*)d_out;
  ma.fb1 = (const float*)d_in[4];  ma.fb2 = (const float*)d_in[6];
  ma.bb1 = (const float*)d_in[12]; ma.bb2 = (const float*)d_in[14]; ma.bb3 = (const float*)d_in[16];
  ma.nb0 = (const float*)d_in[18]; ma.nb2 = (const float*)d_in[20];
  ma.nb4 = (const float*)d_in[22]; ma.nb6 = (const float*)d_in[24]; ma.nb8 = (const float*)d_in[26];
  main_k<<<N_PTS / 64, 256, 0, stream>>>(ma);
}

// Round 6
// 362.119 us; speedup vs baseline: 2.9477x; 1.0942x over previous
//
#include <hip/hip_runtime.h>

#define N_PTS 262144
#define X_STRIDE 79

using floatx4   = __attribute__((ext_vector_type(4))) float;
using floatx4a  = __attribute__((ext_vector_type(4), aligned(4))) float;
using floatx16  = __attribute__((ext_vector_type(16))) float;
using half8     = __attribute__((ext_vector_type(8))) _Float16;
using ushort8v  = __attribute__((ext_vector_type(8))) unsigned short;
using uint2v    = __attribute__((ext_vector_type(2))) unsigned int;

__device__ __forceinline__ unsigned short f2h(float f) {
  _Float16 h = (_Float16)f;
  return __builtin_bit_cast(unsigned short, h);
}
// pack 2 f32 -> 2 f16 in one VALU op (v_cvt_pkrtz_f16_f32)
__device__ __forceinline__ unsigned int pk2(float a, float b) {
  return __builtin_bit_cast(unsigned int, __builtin_amdgcn_cvt_pkrtz(a, b));
}

// ---- weight table: FRAGMENT-MAJOR fp16, 32x32x16 tiles (A operand) ---------
// Layers 0..10: chunk (j, s, lane) at off + ((j*KT + s)*64 + lane)*8 holds
//   W^T[j*32 + (lane&31)][s*16 + (lane>>5)*8 + 0..7], KT = KP/16.
// Layer 11 (nw8): 16x16x32 layout: W^T[j*16+(lane&15)][s*32+(lane>>4)*8+..], KT=KP/32.
// layer:        fw1 fw2 uw1 uw2 bw1 bw2 bw3 nw0 nw2 nw4 nw6 nw8
__device__ const int T_KS[12]  = {63, 64, 63,128,128, 64, 64,140,256,396,256,256};
__device__ const int T_NS[12]  = {64, 64,128, 64, 64, 64, 64,256,256,256,256, 12};
__device__ const int T_KP[12]  = {64, 64, 64,128,128, 64, 64,144,256,400,256,256};
__device__ const int T_OFF[13] = {0,4096,8192,16384,24576,32768,36864,40960,
                                  77824,143360,245760,311296,315392};
#define OFF_FW1 0
#define OFF_FW2 4096
#define OFF_UW1 8192
#define OFF_UW2 16384
#define OFF_BW1 24576
#define OFF_BW2 32768
#define OFF_BW3 36864
#define OFF_NW0 40960
#define OFF_NW2 77824
#define OFF_NW4 143360
#define OFF_NW6 245760
#define OFF_NW8 311296
#define WT_TOTAL 315392

// ---- 32x32x16 MFMA accum: D(features x points) = W^T(A) x X^T(B) -----------
// A frag: A[feat=lane&31][k=(lane>>5)*8+i]  (frag-major wt, contiguous 16B).
// B frag: B[k=(lane>>5)*8+i][pt=lane&31]  -> LDS row(point)-major 16B read.
// D: col=pt=lane&31, row=feat=(reg&3)+8*(reg>>2)+4*(lane>>5).
template<int NJ, int NM>
__device__ __forceinline__ void accum32(floatx16 (&acc)[NJ][NM],
    const unsigned short* ldsB, int strideB, int mrow0,
    const unsigned short* wtL, int KTtot, int jg0,
    int sBegin, int sEnd, int sBBase) {
  const int lane = threadIdx.x & 63;
  const int pr = lane & 31, h = lane >> 5;
#pragma unroll 4
  for (int s = sBegin; s < sEnd; ++s) {
    half8 b[NM];
#pragma unroll
    for (int m = 0; m < NM; ++m)
      b[m] = *reinterpret_cast<const half8*>(
          ldsB + (mrow0 + m * 32 + pr) * strideB + (s - sBBase) * 16 + h * 8);
#pragma unroll
    for (int j = 0; j < NJ; ++j) {
      half8 w = *reinterpret_cast<const half8*>(
          wtL + (size_t)(((jg0 + j) * KTtot + s) * 64 + lane) * 8);
#pragma unroll
      for (int m = 0; m < NM; ++m)
        acc[j][m] = __builtin_amdgcn_mfma_f32_32x32x16_f16(w, b[m], acc[j][m], 0, 0, 0);
    }
  }
}

template<int NJ, int NM>
__device__ __forceinline__ void zero32(floatx16 (&acc)[NJ][NM]) {
#pragma unroll
  for (int j = 0; j < NJ; ++j)
#pragma unroll
    for (int m = 0; m < NM; ++m)
#pragma unroll
      for (int r = 0; r < 16; ++r) acc[j][m][r] = 0.f;
}

// epilogue: 4 reg-groups per tile; pkrtz-packed ds_write_b64 each.
// feature of (j,g,h,r) = colOff + j*32 + g*8 + h*4 + r
template<int NJ, int NM>
__device__ __forceinline__ void epi32(const floatx16 (&acc)[NJ][NM],
    unsigned short* ldsOut, int strideO, int colOff, int mrow0,
    const float* bias, int biasBase, bool relu) {
  const int lane = threadIdx.x & 63;
  const int pr = lane & 31, h = lane >> 5;
#pragma unroll
  for (int j = 0; j < NJ; ++j) {
#pragma unroll
    for (int g = 0; g < 4; ++g) {
      floatx4 b4 = *reinterpret_cast<const floatx4*>(bias + biasBase + j * 32 + g * 8 + h * 4);
#pragma unroll
      for (int m = 0; m < NM; ++m) {
        float v0 = acc[j][m][g * 4 + 0] + b4[0];
        float v1 = acc[j][m][g * 4 + 1] + b4[1];
        float v2 = acc[j][m][g * 4 + 2] + b4[2];
        float v3 = acc[j][m][g * 4 + 3] + b4[3];
        if (relu) {
          v0 = fmaxf(v0, 0.f); v1 = fmaxf(v1, 0.f);
          v2 = fmaxf(v2, 0.f); v3 = fmaxf(v3, 0.f);
        }
        uint2v hv; hv[0] = pk2(v0, v1); hv[1] = pk2(v2, v3);
        *reinterpret_cast<uint2v*>(
            ldsOut + (mrow0 + m * 32 + pr) * strideO + colOff + j * 32 + g * 8 + h * 4) = hv;
      }
    }
  }
}

// 16x16x32 path (kept for nw8 only)
__device__ __forceinline__ void accum16(floatx4& acc,
    const unsigned short* ldsB, int strideB, int mrow0,
    const unsigned short* wtL, int sEnd) {
  const int lane = threadIdx.x & 63;
  const int nh = lane & 15, q = lane >> 4;
#pragma unroll
  for (int s = 0; s < 8; ++s) {
    if (s >= sEnd) break;
    half8 b = *reinterpret_cast<const half8*>(
        ldsB + (mrow0 + nh) * strideB + s * 32 + q * 8);
    half8 w = *reinterpret_cast<const half8*>(
        wtL + (size_t)(s * 64 + lane) * 8);
    acc = __builtin_amdgcn_mfma_f32_16x16x32_f16(w, b, acc, 0, 0, 0);
  }
}

// ---- kernel 1: weight repack + scalar output -------------------------------
struct PrepArgs { const float* src[12]; };

__global__ __launch_bounds__(256) void prep_k(PrepArgs a, unsigned short* wt,
                                              float* outM, float Mval) {
  int chunk = blockIdx.x * 256 + threadIdx.x;  // one thread per 8-half chunk
  if (chunk == 0) *outM = Mval;
  if (chunk >= WT_TOTAL / 8) return;
  int gid = chunk * 8;
  int L = 0;
  while (gid >= T_OFF[L + 1]) ++L;
  int local = chunk - T_OFF[L] / 8;
  int lane = local & 63;
  int t = local >> 6;
  int n, k0;
  if (L < 11) {
    int KT = T_KP[L] >> 4;
    int s = t % KT, j = t / KT;
    n = j * 32 + (lane & 31);
    k0 = s * 16 + (lane >> 5) * 8;
  } else {
    int KT = T_KP[L] >> 5;
    int s = t % KT, j = t / KT;
    n = j * 16 + (lane & 15);
    k0 = s * 32 + (lane >> 4) * 8;
  }
  const float* src = a.src[L];
  int K = T_KS[L], Nn = T_NS[L];
  ushort8v o;
#pragma unroll
  for (int i = 0; i < 8; ++i) {
    int k = k0 + i;
    float v = (k < K && n < Nn) ? src[(size_t)k * Nn + n] : 0.f;
    o[i] = f2h(v);
  }
  *reinterpret_cast<ushort8v*>(wt + gid) = o;
}

// ---- kernel 2: voxel branch, 64 voxels/block -------------------------------
__global__ __launch_bounds__(256, 3) void voxel_k(const float* __restrict__ x,
                                                  const int* __restrict__ inds,
                                                  const unsigned short* __restrict__ wt,
                                                  const float* __restrict__ ub1,
                                                  const float* __restrict__ ub2,
                                                  unsigned short* __restrict__ vout, int M) {
  __shared__ unsigned short bufV[64 * 72];
  __shared__ unsigned short bufU[64 * 136];
  const int wave = threadIdx.x >> 6, lane = threadIdx.x & 63;
  const int pr = lane & 31, h = lane >> 5;
  const int v0 = blockIdx.x * 64;

  // gather: 16 float4 groups per voxel row (cols 0..63, col 63 zeroed)
  for (int idx = threadIdx.x; idx < 64 * 16; idx += 256) {
    int p = idx >> 4, g = idx & 15;
    int v = v0 + p;
    uint2v hv; hv[0] = 0u; hv[1] = 0u;
    if (v < M) {
      floatx4a f = *reinterpret_cast<const floatx4a*>(
          x + (size_t)inds[v] * X_STRIDE + g * 4);
      if (g == 15) f[3] = 0.f;  // col 63 is padding (K=63)
      hv[0] = pk2(f[0], f[1]); hv[1] = pk2(f[2], f[3]);
    }
    *reinterpret_cast<uint2v*>(bufV + p * 72 + g * 4) = hv;
  }
  __syncthreads();

  // uw1: 63->128 relu
  {
    floatx16 acc[2][1];
    zero32<2, 1>(acc);
    int jg0 = (wave & 1) * 2, m0 = (wave >> 1) * 32;
    accum32<2, 1>(acc, bufV, 72, m0, wt + OFF_UW1, 4, jg0, 0, 4, 0);
    epi32<2, 1>(acc, bufU, 136, jg0 * 32, m0, ub1, jg0 * 32, true);
  }
  __syncthreads();

  // uw2: 128->64, direct global store (pkrtz-packed b64)
  {
    floatx16 acc[1][1];
    zero32<1, 1>(acc);
    int j = wave & 1, m0 = (wave >> 1) * 32;
    accum32<1, 1>(acc, bufU, 136, m0, wt + OFF_UW2, 8, j, 0, 8, 0);
    int v = v0 + m0 + pr;
    if (v < M) {
#pragma unroll
      for (int g = 0; g < 4; ++g) {
        floatx4 b4 = *reinterpret_cast<const floatx4*>(ub2 + j * 32 + g * 8 + h * 4);
        uint2v hv;
        hv[0] = pk2(acc[0][0][g * 4 + 0] + b4[0], acc[0][0][g * 4 + 1] + b4[1]);
        hv[1] = pk2(acc[0][0][g * 4 + 2] + b4[2], acc[0][0][g * 4 + 3] + b4[3]);
        *reinterpret_cast<uint2v*>(vout + (size_t)v * 64 + j * 32 + g * 8 + h * 4) = hv;
      }
    }
  }
}

// ---- kernel 3: fused per-point pipeline, 64 pts/block ----------------------
// LDS rows = points. bufX[64][152]: x [0,76) | back [76,140) | zero [140,152).
// reg2[64][264]: front [0,64) / pcd [64,128) / t1 [128,192) / t2 [192,256)
struct MainArgs {
  const float* x;
  const int* invmap;
  const unsigned short* wt;
  const unsigned short* vout;
  float* out;
  const float* fb1; const float* fb2;
  const float* bb1; const float* bb2; const float* bb3;
  const float* nb0; const float* nb2; const float* nb4; const float* nb6; const float* nb8;
};

__global__ __launch_bounds__(256, 3) void main_k(MainArgs a) {
  __shared__ unsigned short bufX[64 * 152];
  __shared__ unsigned short reg2[64 * 264];
  const int wave = threadIdx.x >> 6, lane = threadIdx.x & 63;
  const int p0 = blockIdx.x * 64;

  // stage x[:, :76): 19 float4 groups/row, pkrtz-packed b64 LDS writes
  for (int idx = threadIdx.x; idx < 64 * 19; idx += 256) {
    int p = idx / 19, g = idx - p * 19;
    floatx4a f = *reinterpret_cast<const floatx4a*>(
        a.x + (size_t)(p0 + p) * X_STRIDE + g * 4);
    uint2v hv; hv[0] = pk2(f[0], f[1]); hv[1] = pk2(f[2], f[3]);
    *reinterpret_cast<uint2v*>(bufX + p * 152 + g * 4) = hv;
  }
  // zero bufX cols [140,152)
  for (int idx = threadIdx.x; idx < 64 * 3; idx += 256) {
    int p = idx / 3, c = (idx - p * 3) * 4;
    uint2v z; z[0] = 0u; z[1] = 0u;
    *reinterpret_cast<uint2v*>(bufX + p * 152 + 140 + c) = z;
  }
  // gather pcd -> reg2 cols [64,128)
  for (int idx = threadIdx.x; idx < 64 * 8; idx += 256) {
    int p = idx >> 3, c = (idx & 7) * 8;
    int r = a.invmap[p0 + p];
    *reinterpret_cast<ushort8v*>(reg2 + p * 264 + 64 + c) =
        *reinterpret_cast<const ushort8v*>(a.vout + (size_t)r * 64 + c);
  }
  __syncthreads();

  const int jw = wave & 1, mw = (wave >> 1) * 32;  // for 64-wide layers

  // fw1: pe -> 64 relu -> reg2 t1 [128,192)
  {
    floatx16 acc[1][1];
    zero32<1, 1>(acc);
    accum32<1, 1>(acc, bufX, 152, mw, a.wt + OFF_FW1, 4, jw, 0, 4, 0);
    epi32<1, 1>(acc, reg2, 264, 128 + jw * 32, mw, a.fb1, jw * 32, true);
  }
  __syncthreads();
  // fw2: t1 -> front [0,64)
  {
    floatx16 acc[1][1];
    zero32<1, 1>(acc);
    accum32<1, 1>(acc, reg2 + 128, 264, mw, a.wt + OFF_FW2, 4, jw, 0, 4, 0);
    epi32<1, 1>(acc, reg2, 264, jw * 32, mw, a.fb2, jw * 32, false);
  }
  __syncthreads();
  // bw1: [front|pcd](128) -> 64 relu -> t1
  {
    floatx16 acc[1][1];
    zero32<1, 1>(acc);
    accum32<1, 1>(acc, reg2, 264, mw, a.wt + OFF_BW1, 8, jw, 0, 8, 0);
    epi32<1, 1>(acc, reg2, 264, 128 + jw * 32, mw, a.bb1, jw * 32, true);
  }
  __syncthreads();
  // bw2: t1 -> 64 relu -> t2 [192,256)
  {
    floatx16 acc[1][1];
    zero32<1, 1>(acc);
    accum32<1, 1>(acc, reg2 + 128, 264, mw, a.wt + OFF_BW2, 4, jw, 0, 4, 0);
    epi32<1, 1>(acc, reg2, 264, 192 + jw * 32, mw, a.bb2, jw * 32, true);
  }
  __syncthreads();
  // bw3: t2 -> back -> bufX cols [76,140)
  {
    floatx16 acc[1][1];
    zero32<1, 1>(acc);
    accum32<1, 1>(acc, reg2 + 192, 264, mw, a.wt + OFF_BW3, 4, jw, 0, 4, 0);
    epi32<1, 1>(acc, bufX, 152, 76 + jw * 32, mw, a.bb3, jw * 32, false);
  }
  __syncthreads();

  // 256-wide: each wave NJ=2 (features wave*64..+64), NM=2 (all 64 pts)
  // n0: xx(144) -> 256 relu -> reg2[0:256)
  {
    floatx16 acc[2][2];
    zero32<2, 2>(acc);
    accum32<2, 2>(acc, bufX, 152, 0, a.wt + OFF_NW0, 9, wave * 2, 0, 9, 0);
    epi32<2, 2>(acc, reg2, 264, wave * 64, 0, a.nb0, wave * 64, true);
  }
  __syncthreads();
  // n2: 256 -> 256 relu, in-place
  {
    floatx16 acc[2][2];
    zero32<2, 2>(acc);
    accum32<2, 2>(acc, reg2, 264, 0, a.wt + OFF_NW2, 16, wave * 2, 0, 16, 0);
    __syncthreads();
    epi32<2, 2>(acc, reg2, 264, wave * 64, 0, a.nb2, wave * 64, true);
  }
  __syncthreads();
  // n4: [h(256)|xx(144)] -> 256 relu, in-place
  {
    floatx16 acc[2][2];
    zero32<2, 2>(acc);
    accum32<2, 2>(acc, reg2, 264, 0, a.wt + OFF_NW4, 25, wave * 2, 0, 16, 0);
    accum32<2, 2>(acc, bufX, 152, 0, a.wt + OFF_NW4, 25, wave * 2, 16, 25, 16);
    __syncthreads();
    epi32<2, 2>(acc, reg2, 264, wave * 64, 0, a.nb4, wave * 64, true);
  }
  __syncthreads();
  // n6: 256 -> 256 relu, in-place
  {
    floatx16 acc[2][2];
    zero32<2, 2>(acc);
    accum32<2, 2>(acc, reg2, 264, 0, a.wt + OFF_NW6, 16, wave * 2, 0, 16, 0);
    __syncthreads();
    epi32<2, 2>(acc, reg2, 264, wave * 64, 0, a.nb6, wave * 64, true);
  }
  __syncthreads();
  // n8: 256 -> 12 via 16x16x32; wave -> m-tile of 16 pts; direct global store
  {
    const int nh = lane & 15, q = lane >> 4;
    floatx4 acc = {0.f, 0.f, 0.f, 0.f};
    accum16(acc, reg2, 264, wave * 16, a.wt + OFF_NW8, 8);
    if (q < 3) {
      floatx4 o;
#pragma unroll
      for (int r = 0; r < 4; ++r) o[r] = acc[r] + a.nb8[q * 4 + r];
      *reinterpret_cast<floatx4*>(a.out + (size_t)(p0 + wave * 16 + nh) * 12 + q * 4) = o;
    }
  }
}

// ---- launch ----------------------------------------------------------------
extern "C" void kernel_launch(void* const* d_in, const int* in_sizes, int n_in,
                              void* d_out, int out_size, void* d_ws, size_t ws_size,
                              hipStream_t stream) {
  const float* x      = (const float*)d_in[0];
  const int*   inds   = (const int*)d_in[1];
  const int*   invmap = (const int*)d_in[2];
  const int M = in_sizes[1];

  unsigned short* wt   = (unsigned short*)d_ws;                       // 631 KB
  unsigned short* vout = (unsigned short*)((char*)d_ws + (1 << 20));  // M*64*2

  PrepArgs pa;
  pa.src[0]  = (const float*)d_in[3];   // fw1
  pa.src[1]  = (const float*)d_in[5];   // fw2
  pa.src[2]  = (const float*)d_in[7];   // uw1
  pa.src[3]  = (const float*)d_in[9];   // uw2
  pa.src[4]  = (const float*)d_in[11];  // bw1
  pa.src[5]  = (const float*)d_in[13];  // bw2
  pa.src[6]  = (const float*)d_in[15];  // bw3
  pa.src[7]  = (const float*)d_in[17];  // nw0
  pa.src[8]  = (const float*)d_in[19];  // nw2
  pa.src[9]  = (const float*)d_in[21];  // nw4
  pa.src[10] = (const float*)d_in[23];  // nw6
  pa.src[11] = (const float*)d_in[25];  // nw8

  float* outM = (float*)d_out + (size_t)N_PTS * 12;
  prep_k<<<(WT_TOTAL / 8 + 255) / 256, 256, 0, stream>>>(pa, wt, outM, (float)M);

  voxel_k<<<(M + 63) / 64, 256, 0, stream>>>(x, inds, wt,
                                             (const float*)d_in[8],   // ub1
                                             (const float*)d_in[10],  // ub2
                                             vout, M);

  MainArgs ma;
  ma.x = x; ma.invmap = invmap; ma.wt = wt; ma.vout = vout; ma.out = (float*)d_out;
  ma.fb1 = (const float*)d_in[4];  ma.fb2 = (const float*)d_in[6];
  ma.bb1 = (const float*)d_in[12]; ma.bb2 = (const float*)d_in[14]; ma.bb3 = (const float*)d_in[16];
  ma.nb0 = (const float*)d_in[18]; ma.nb2 = (const float*)d_in[20];
  ma.nb4 = (const float*)d_in[22]; ma.nb6 = (const float*)d_in[24]; ma.nb8 = (const float*)d_in[26];
  main_k<<<N_PTS / 64, 256, 0, stream>>>(ma);
}